// Round 1
// baseline (199.499 us; speedup 1.0000x reference)
//
#include <hip/hip_runtime.h>
#include <hip/hip_bf16.h>

typedef _Float16 half8 __attribute__((ext_vector_type(8)));
typedef float    floatx4 __attribute__((ext_vector_type(4)));

#define WSCALE      4096.0f
#define WSCALE_INV  (1.0f/(4096.0f*4096.0f))

// ws layout (float offsets)
#define S0_OFF   0      // 256 floats  (1,16,4,4)
#define S1_OFF   256    // 4096        (16,16,4,4)
#define S2_OFF   4352   // 4096
#define S3_OFF   8448   // 256         (16,1,4,4)
#define T1_OFF   8704   // 4096        (16,16,16)
#define T2_OFF   12800  // 65536       (16,64,64)
#define WT16_OFF 78336  // 65536 _Float16 = 32768 floats; 16B-aligned

// ---- Pair-contract adjacent MPO cores into 4 supercores (l,r,4,4) ----
__global__ void mpo_pairs(const float* __restrict__ w, float* __restrict__ ws) {
    int idx = blockIdx.x * blockDim.x + threadIdx.x;
    int p, base, r, outoff;
    if      (idx < 256)  { p = 0; base = 0;    r = 16; outoff = S0_OFF; }
    else if (idx < 4352) { p = 1; base = 256;  r = 16; outoff = S1_OFF; }
    else if (idx < 8448) { p = 2; base = 4352; r = 16; outoff = S2_OFF; }
    else if (idx < 8704) { p = 3; base = 8448; r = 1;  outoff = S3_OFF; }
    else return;
    int li = idx - base;
    int mm = li & 3, kk = (li >> 2) & 3, ac = li >> 4;
    int c = ac % r, a = ac / r;
    int k1 = kk >> 1, k2 = kk & 1, m1 = mm >> 1, m2 = mm & 1;
    const int coreoff[8] = {0, 64, 1088, 2112, 3136, 4160, 5184, 6208};
    const float* A = w + coreoff[2 * p];       // (l,16,2,2)
    const float* B = w + coreoff[2 * p + 1];   // (16,r,2,2)
    float s = 0.f;
    for (int b = 0; b < 16; ++b)
        s += A[((a * 16 + b) * 2 + k1) * 2 + m1] * B[((b * r + c) * 2 + k2) * 2 + m2];
    ws[outoff + li] = s;   // S[a][c][k1*2+k2][m1*2+m2]
}

// ---- Generic TT step: T(16,dim,dim) x S(16,r,4,4) -> out(r,4dim,4dim) ----
__global__ void mpo_step(const float* __restrict__ T, const float* __restrict__ S,
                         float* __restrict__ out, int r, int dim) {
    int idx = blockIdx.x * blockDim.x + threadIdx.x;
    int D4 = dim * 4;
    int total = r * D4 * D4;
    if (idx >= total) return;
    int J4 = idx % D4; int t = idx / D4; int I4 = t % D4; int b = t / D4;
    int I = I4 >> 2, k = I4 & 3, J = J4 >> 2, m = J4 & 3;
    float s = 0.f;
    for (int a = 0; a < 16; ++a)
        s += T[(a * dim + I) * dim + J] * S[((a * r + b) * 4 + k) * 4 + m];
    out[idx] = s;
}

// ---- Final step fused with transpose+scale+fp16: Wt[n][k] = W[k][n]*4096 ----
__global__ void mpo_step_final(const float* __restrict__ T, const float* __restrict__ S,
                               _Float16* __restrict__ Wt) {
    int idx = blockIdx.x * blockDim.x + threadIdx.x;  // 65536
    int J4 = idx & 255; int I4 = idx >> 8;
    int I = I4 >> 2, k = I4 & 3, J = J4 >> 2, m = J4 & 3;
    float s = 0.f;
    for (int a = 0; a < 16; ++a)
        s += T[(a * 64 + I) * 64 + J] * S[(a * 4 + k) * 4 + m];
    Wt[J4 * 256 + I4] = (_Float16)(s * WSCALE);
}

// ---- Main fused kernel: y = x@W (fp16 MFMA), out = sum(y^2 * dk) + bias ----
__global__ __launch_bounds__(512, 4)
void mpo_main(const float* __restrict__ x, const _Float16* __restrict__ Wt,
              const float* __restrict__ dk, const float* __restrict__ bias,
              float* __restrict__ out, int rows_per_block) {
    __shared__ __align__(16) _Float16 Wl[128 * 256];   // 64 KB, swizzled half of W^T

    const int tid  = threadIdx.x;
    const int lane = tid & 63;
    const int wave = tid >> 6;
    const int lrow = lane & 15;   // A row / B,C col within tile
    const int g    = lane >> 4;   // k-group

    float kreg[16];
#pragma unroll
    for (int n = 0; n < 16; ++n) kreg[n] = dk[n * 16 + lrow];
    const float bs = bias[0];

    const long blockrow = (long)blockIdx.x * rows_per_block;

    for (int pr = 0; pr < rows_per_block; pr += 256) {
        const long wrow = blockrow + pr + wave * 32;

        // Load 32 rows x 256 K of x, convert fp32->fp16 (2 A-fragment sets)
        half8 a[2][8];
#pragma unroll
        for (int s = 0; s < 2; ++s) {
            const float* xs = x + (wrow + s * 16 + lrow) * 256 + g * 8;
#pragma unroll
            for (int kk = 0; kk < 8; ++kk) {
                floatx4 lo = *reinterpret_cast<const floatx4*>(xs + kk * 32);
                floatx4 hi = *reinterpret_cast<const floatx4*>(xs + kk * 32 + 4);
                half8 f;
                f[0] = (_Float16)lo[0]; f[1] = (_Float16)lo[1];
                f[2] = (_Float16)lo[2]; f[3] = (_Float16)lo[3];
                f[4] = (_Float16)hi[0]; f[5] = (_Float16)hi[1];
                f[6] = (_Float16)hi[2]; f[7] = (_Float16)hi[3];
                a[s][kk] = f;
            }
        }

        float rp[2][4] = {{0, 0, 0, 0}, {0, 0, 0, 0}};

#pragma unroll
        for (int hf = 0; hf < 2; ++hf) {
            __syncthreads();   // previous half's reads (or prev pass) done
            // Stage 64 KB: W^T rows [hf*128, hf*128+128), XOR-swizzled
#pragma unroll
            for (int i = 0; i < 8; ++i) {
                int c    = tid + i * 512;      // 16B chunk id (0..4095)
                int nloc = c >> 5;             // LDS row
                int cin  = c & 31;             // chunk within row
                floatx4 v = *reinterpret_cast<const floatx4*>(
                    reinterpret_cast<const float*>(Wt + hf * 32768) + c * 4);
                int dst = (nloc << 9) | ((cin << 4) ^ ((nloc & 7) << 4));
                *reinterpret_cast<floatx4*>(reinterpret_cast<char*>(Wl) + dst) = v;
            }
            __syncthreads();

#pragma unroll
            for (int n = 0; n < 8; ++n) {
                const int ns   = hf * 8 + n;        // global col strip
                const int nloc = n * 16 + lrow;     // LDS row = col within half
                const int rowbyte = nloc << 9;
                const int swz     = (nloc & 7) << 4;
                floatx4 c0 = {0, 0, 0, 0}, c1 = {0, 0, 0, 0};
#pragma unroll
                for (int kk = 0; kk < 8; ++kk) {
                    const int kbyte = (kk * 64 + g * 16) ^ swz;
                    half8 b = *reinterpret_cast<const half8*>(
                        reinterpret_cast<const char*>(Wl) + (rowbyte | kbyte));
                    c0 = __builtin_amdgcn_mfma_f32_16x16x32_f16(a[0][kk], b, c0, 0, 0, 0);
                    c1 = __builtin_amdgcn_mfma_f32_16x16x32_f16(a[1][kk], b, c1, 0, 0, 0);
                }
                const float kv = kreg[ns];
#pragma unroll
                for (int r = 0; r < 4; ++r) {
                    rp[0][r] += c0[r] * c0[r] * kv;
                    rp[1][r] += c1[r] * c1[r] * kv;
                }
            }
        }

        // Reduce over the 16 cols (lanes sharing g), then store
#pragma unroll
        for (int s = 0; s < 2; ++s)
#pragma unroll
            for (int r = 0; r < 4; ++r) {
                float v = rp[s][r];
                v += __shfl_xor(v, 1);
                v += __shfl_xor(v, 2);
                v += __shfl_xor(v, 4);
                v += __shfl_xor(v, 8);
                rp[s][r] = v;
            }
        if (lrow == 0) {
#pragma unroll
            for (int s = 0; s < 2; ++s)
#pragma unroll
                for (int r = 0; r < 4; ++r)
                    out[wrow + s * 16 + g * 4 + r] = rp[s][r] * WSCALE_INV + bs;
        }
    }
}

extern "C" void kernel_launch(void* const* d_in, const int* in_sizes, int n_in,
                              void* d_out, int out_size, void* d_ws, size_t ws_size,
                              hipStream_t stream) {
    const float* x    = (const float*)d_in[0];
    const float* w    = (const float*)d_in[1];
    const float* dk   = (const float*)d_in[2];
    const float* bias = (const float*)d_in[3];
    float* out = (float*)d_out;
    float* ws  = (float*)d_ws;

    _Float16* Wt16 = (_Float16*)(ws + WT16_OFF);

    // W contraction (tiny)
    mpo_pairs<<<(8704 + 255) / 256, 256, 0, stream>>>(w, ws);
    mpo_step<<<(4096 + 255) / 256, 256, 0, stream>>>(ws + S0_OFF, ws + S1_OFF, ws + T1_OFF, 16, 4);
    mpo_step<<<(65536 + 255) / 256, 256, 0, stream>>>(ws + T1_OFF, ws + S2_OFF, ws + T2_OFF, 16, 16);
    mpo_step_final<<<(65536 + 255) / 256, 256, 0, stream>>>(ws + T2_OFF, ws + S3_OFF, Wt16);

    // Main fused GEMM + square + dot
    const int n_rows = in_sizes[0] / 256;      // 262144
    const int grid = 512;
    const int rows_per_block = n_rows / grid;  // 512 (multiple of 256)
    mpo_main<<<grid, 512, 0, stream>>>(x, Wt16, dk, bias, out, rows_per_block);
}

// Round 2
// 177.410 us; speedup vs baseline: 1.1245x; 1.1245x over previous
//
#include <hip/hip_runtime.h>
#include <hip/hip_bf16.h>

typedef _Float16 half8 __attribute__((ext_vector_type(8)));
typedef float    floatx4 __attribute__((ext_vector_type(4)));

#define WSCALE      4096.0f
#define WSCALE_INV  (1.0f/(4096.0f*4096.0f))

// ws layout (float offsets)
#define S0_OFF   0      // 256 floats  (1,16,4,4)
#define S1_OFF   256    // 4096        (16,16,4,4)
#define S2_OFF   4352   // 4096
#define S3_OFF   8448   // 256         (16,1,4,4)
#define T1_OFF   8704   // 4096        (16,16,16)
#define T2_OFF   12800  // 65536       (16,64,64)
#define WF16_OFF 78336  // 65536 _Float16, fragment-major; 16B-aligned

// ---- Pair-contract adjacent MPO cores into 4 supercores (l,r,4,4) ----
__global__ void mpo_pairs(const float* __restrict__ w, float* __restrict__ ws) {
    int idx = blockIdx.x * blockDim.x + threadIdx.x;
    int p, base, r, outoff;
    if      (idx < 256)  { p = 0; base = 0;    r = 16; outoff = S0_OFF; }
    else if (idx < 4352) { p = 1; base = 256;  r = 16; outoff = S1_OFF; }
    else if (idx < 8448) { p = 2; base = 4352; r = 16; outoff = S2_OFF; }
    else if (idx < 8704) { p = 3; base = 8448; r = 1;  outoff = S3_OFF; }
    else return;
    int li = idx - base;
    int mm = li & 3, kk = (li >> 2) & 3, ac = li >> 4;
    int c = ac % r, a = ac / r;
    int k1 = kk >> 1, k2 = kk & 1, m1 = mm >> 1, m2 = mm & 1;
    const int coreoff[8] = {0, 64, 1088, 2112, 3136, 4160, 5184, 6208};
    const float* A = w + coreoff[2 * p];       // (l,16,2,2)
    const float* B = w + coreoff[2 * p + 1];   // (16,r,2,2)
    float s = 0.f;
    for (int b = 0; b < 16; ++b)
        s += A[((a * 16 + b) * 2 + k1) * 2 + m1] * B[((b * r + c) * 2 + k2) * 2 + m2];
    ws[outoff + li] = s;   // S[a][c][k1*2+k2][m1*2+m2]
}

// ---- Generic TT step: T(16,dim,dim) x S(16,r,4,4) -> out(r,4dim,4dim) ----
__global__ void mpo_step(const float* __restrict__ T, const float* __restrict__ S,
                         float* __restrict__ out, int r, int dim) {
    int idx = blockIdx.x * blockDim.x + threadIdx.x;
    int D4 = dim * 4;
    int total = r * D4 * D4;
    if (idx >= total) return;
    int J4 = idx % D4; int t = idx / D4; int I4 = t % D4; int b = t / D4;
    int I = I4 >> 2, k = I4 & 3, J = J4 >> 2, m = J4 & 3;
    float s = 0.f;
    for (int a = 0; a < 16; ++a)
        s += T[(a * dim + I) * dim + J] * S[((a * r + b) * 4 + k) * 4 + m];
    out[idx] = s;
}

// ---- Final step fused with scale + fp16 + FRAGMENT-MAJOR layout ----
// W[k=I4][col=J4]; fragment index: strip n=col>>4, lrow=col&15,
// kk=k>>5, g=(k>>3)&3, j=k&7.  Lane (g*16+lrow) of read (n,kk) gets 8
// contiguous halves -> wave read is lane-linear 1024B.
__global__ void mpo_step_final(const float* __restrict__ T, const float* __restrict__ S,
                               _Float16* __restrict__ Wf) {
    int idx = blockIdx.x * blockDim.x + threadIdx.x;  // 65536
    int J4 = idx & 255; int I4 = idx >> 8;            // col, k
    int I = I4 >> 2, k = I4 & 3, J = J4 >> 2, m = J4 & 3;
    float s = 0.f;
    for (int a = 0; a < 16; ++a)
        s += T[(a * 64 + I) * 64 + J] * S[(a * 4 + k) * 4 + m];
    int n = J4 >> 4, lr = J4 & 15, kk = I4 >> 5, gg = (I4 >> 3) & 3, j = I4 & 7;
    Wf[(((n * 8 + kk) * 64) + gg * 16 + lr) * 8 + j] = (_Float16)(s * WSCALE);
}

// ---- Main fused kernel: no LDS, no barriers. Each wave owns 32 rows. ----
// B fragments read straight from global (128KB, L2/L1-resident; all waves
// read identical addresses -> L1 broadcast).
__global__ __launch_bounds__(256, 4)
void mpo_main(const float* __restrict__ x, const _Float16* __restrict__ Wf,
              const float* __restrict__ dk, const float* __restrict__ bias,
              float* __restrict__ out) {
    const int tid  = threadIdx.x;
    const int lane = tid & 63;
    const int wave = tid >> 6;
    const int lrow = lane & 15;   // A row / B,C col within tile
    const int g    = lane >> 4;   // k-group

    const long gw   = (long)blockIdx.x * 4 + wave;
    const long wrow = gw * 32;

    float kreg[16];
#pragma unroll
    for (int n = 0; n < 16; ++n) kreg[n] = dk[n * 16 + lrow];
    const float bs = bias[0];

    // Load 32 rows x 256 K of x, convert fp32->fp16 (2 A-fragment sets)
    half8 a[2][8];
#pragma unroll
    for (int s = 0; s < 2; ++s) {
        const float* xs = x + (wrow + s * 16 + lrow) * 256 + g * 8;
#pragma unroll
        for (int kk = 0; kk < 8; ++kk) {
            floatx4 lo = *reinterpret_cast<const floatx4*>(xs + kk * 32);
            floatx4 hi = *reinterpret_cast<const floatx4*>(xs + kk * 32 + 4);
            half8 f;
            f[0] = (_Float16)lo[0]; f[1] = (_Float16)lo[1];
            f[2] = (_Float16)lo[2]; f[3] = (_Float16)lo[3];
            f[4] = (_Float16)hi[0]; f[5] = (_Float16)hi[1];
            f[6] = (_Float16)hi[2]; f[7] = (_Float16)hi[3];
            a[s][kk] = f;
        }
    }

    float rp[2][4] = {{0, 0, 0, 0}, {0, 0, 0, 0}};
    const half8* Wv = reinterpret_cast<const half8*>(Wf);

#pragma unroll
    for (int n = 0; n < 16; ++n) {
        floatx4 c0 = {0, 0, 0, 0}, c1 = {0, 0, 0, 0};
#pragma unroll
        for (int kk = 0; kk < 8; ++kk) {
            half8 b = Wv[(n * 8 + kk) * 64 + lane];
            c0 = __builtin_amdgcn_mfma_f32_16x16x32_f16(a[0][kk], b, c0, 0, 0, 0);
            c1 = __builtin_amdgcn_mfma_f32_16x16x32_f16(a[1][kk], b, c1, 0, 0, 0);
        }
        const float kv = kreg[n];
#pragma unroll
        for (int r = 0; r < 4; ++r) {
            rp[0][r] += c0[r] * c0[r] * kv;
            rp[1][r] += c1[r] * c1[r] * kv;
        }
    }

    // Reduce over the 16 cols (lanes sharing g): shfl over lrow bits
#pragma unroll
    for (int s = 0; s < 2; ++s)
#pragma unroll
        for (int r = 0; r < 4; ++r) {
            float v = rp[s][r];
            v += __shfl_xor(v, 1);
            v += __shfl_xor(v, 2);
            v += __shfl_xor(v, 4);
            v += __shfl_xor(v, 8);
            rp[s][r] = v;
        }
    if (lrow == 0) {
#pragma unroll
        for (int s = 0; s < 2; ++s) {
            floatx4 o;
#pragma unroll
            for (int r = 0; r < 4; ++r) o[r] = rp[s][r] * WSCALE_INV + bs;
            *reinterpret_cast<floatx4*>(out + wrow + s * 16 + g * 4) = o;
        }
    }
}

extern "C" void kernel_launch(void* const* d_in, const int* in_sizes, int n_in,
                              void* d_out, int out_size, void* d_ws, size_t ws_size,
                              hipStream_t stream) {
    const float* x    = (const float*)d_in[0];
    const float* w    = (const float*)d_in[1];
    const float* dk   = (const float*)d_in[2];
    const float* bias = (const float*)d_in[3];
    float* out = (float*)d_out;
    float* ws  = (float*)d_ws;

    _Float16* Wf16 = (_Float16*)(ws + WF16_OFF);

    // W contraction (tiny)
    mpo_pairs<<<(8704 + 255) / 256, 256, 0, stream>>>(w, ws);
    mpo_step<<<(4096 + 255) / 256, 256, 0, stream>>>(ws + S0_OFF, ws + S1_OFF, ws + T1_OFF, 16, 4);
    mpo_step<<<(65536 + 255) / 256, 256, 0, stream>>>(ws + T1_OFF, ws + S2_OFF, ws + T2_OFF, 16, 16);
    mpo_step_final<<<(65536 + 255) / 256, 256, 0, stream>>>(ws + T2_OFF, ws + S3_OFF, Wf16);

    // Main fused GEMM + square + dot: 262144 rows / 32 per wave / 4 waves per block
    const int n_rows = in_sizes[0] / 256;          // 262144
    const int grid   = n_rows / (32 * 4);          // 2048
    mpo_main<<<grid, 256, 0, stream>>>(x, Wf16, dk, bias, out);
}

// Round 3
// 170.076 us; speedup vs baseline: 1.1730x; 1.0431x over previous
//
#include <hip/hip_runtime.h>
#include <hip/hip_bf16.h>

typedef _Float16 half8 __attribute__((ext_vector_type(8)));
typedef float    floatx4 __attribute__((ext_vector_type(4)));

#define WSCALE      4096.0f
#define WSCALE_INV  (1.0f/(4096.0f*4096.0f))

// ws layout (float offsets)
#define S0_OFF   0      // 256 floats  (1,16,4,4)
#define S1_OFF   256    // 4096        (16,16,4,4)
#define S2_OFF   4352   // 4096
#define S3_OFF   8448   // 256         (16,1,4,4)
#define T1_OFF   8704   // 4096        (16,16,16)
#define T2_OFF   12800  // 65536       (16,64,64)
#define WF16_OFF 78336  // 65536 _Float16, fragment-major; 16B-aligned

// ---- Pair-contract adjacent MPO cores into 4 supercores (l,r,4,4) ----
__global__ void mpo_pairs(const float* __restrict__ w, float* __restrict__ ws) {
    int idx = blockIdx.x * blockDim.x + threadIdx.x;
    int p, base, r, outoff;
    if      (idx < 256)  { p = 0; base = 0;    r = 16; outoff = S0_OFF; }
    else if (idx < 4352) { p = 1; base = 256;  r = 16; outoff = S1_OFF; }
    else if (idx < 8448) { p = 2; base = 4352; r = 16; outoff = S2_OFF; }
    else if (idx < 8704) { p = 3; base = 8448; r = 1;  outoff = S3_OFF; }
    else return;
    int li = idx - base;
    int mm = li & 3, kk = (li >> 2) & 3, ac = li >> 4;
    int c = ac % r, a = ac / r;
    int k1 = kk >> 1, k2 = kk & 1, m1 = mm >> 1, m2 = mm & 1;
    const int coreoff[8] = {0, 64, 1088, 2112, 3136, 4160, 5184, 6208};
    const float* A = w + coreoff[2 * p];       // (l,16,2,2)
    const float* B = w + coreoff[2 * p + 1];   // (16,r,2,2)
    float s = 0.f;
    for (int b = 0; b < 16; ++b)
        s += A[((a * 16 + b) * 2 + k1) * 2 + m1] * B[((b * r + c) * 2 + k2) * 2 + m2];
    ws[outoff + li] = s;   // S[a][c][k1*2+k2][m1*2+m2]
}

// ---- Generic TT step: T(16,dim,dim) x S(16,r,4,4) -> out(r,4dim,4dim) ----
__global__ void mpo_step(const float* __restrict__ T, const float* __restrict__ S,
                         float* __restrict__ out, int r, int dim) {
    int idx = blockIdx.x * blockDim.x + threadIdx.x;
    int D4 = dim * 4;
    int total = r * D4 * D4;
    if (idx >= total) return;
    int J4 = idx % D4; int t = idx / D4; int I4 = t % D4; int b = t / D4;
    int I = I4 >> 2, k = I4 & 3, J = J4 >> 2, m = J4 & 3;
    float s = 0.f;
    for (int a = 0; a < 16; ++a)
        s += T[(a * dim + I) * dim + J] * S[((a * r + b) * 4 + k) * 4 + m];
    out[idx] = s;
}

// ---- Final step fused with scale + fp16 + FRAGMENT-MAJOR layout ----
// W[k=I4][col=J4]; fragment index: strip n=col>>4, lrow=col&15,
// kk=k>>5, g=(k>>3)&3, j=k&7.  Lane (g*16+lrow) of read (n,kk) gets 8
// contiguous halves -> wave read is lane-linear 1024B.
__global__ void mpo_step_final(const float* __restrict__ T, const float* __restrict__ S,
                               _Float16* __restrict__ Wf) {
    int idx = blockIdx.x * blockDim.x + threadIdx.x;  // 65536
    int J4 = idx & 255; int I4 = idx >> 8;            // col, k
    int I = I4 >> 2, k = I4 & 3, J = J4 >> 2, m = J4 & 3;
    float s = 0.f;
    for (int a = 0; a < 16; ++a)
        s += T[(a * 64 + I) * 64 + J] * S[(a * 4 + k) * 4 + m];
    int n = J4 >> 4, lr = J4 & 15, kk = I4 >> 5, gg = (I4 >> 3) & 3, j = I4 & 7;
    Wf[(((n * 8 + kk) * 64) + gg * 16 + lr) * 8 + j] = (_Float16)(s * WSCALE);
}

// ---- Main fused kernel: no LDS, no barriers. Each wave owns 32 rows. ----
// x load+cvt is an explicitly pipelined 16-step sequence (loads 4 steps
// ahead, sched_barrier(0)-pinned) so only ~8 floatx4 temporaries are live
// at once -> no scratch spill (R2's 214MB WRITE_SIZE pathology).
__global__ __launch_bounds__(256, 4)
void mpo_main(const float* __restrict__ x, const _Float16* __restrict__ Wf,
              const float* __restrict__ dk, const float* __restrict__ bias,
              float* __restrict__ out) {
    const int tid  = threadIdx.x;
    const int lane = tid & 63;
    const int wave = tid >> 6;
    const int lrow = lane & 15;   // A row / B,C col within tile
    const int g    = lane >> 4;   // k-group

    const long gw   = (long)blockIdx.x * 4 + wave;
    const long wrow = gw * 32;

    float kreg[16];
#pragma unroll
    for (int n = 0; n < 16; ++n) kreg[n] = dk[n * 16 + lrow];
    const float bs = bias[0];

    // ---- Pipelined load+convert of 32 rows x 256 K of x ----
    // fragment i: s=i>>3, kk=i&7; addr = (wrow + s*16 + lrow)*256 + g*8 + kk*32
    half8 a[2][8];
    floatx4 lo[16], hi[16];
    const float* xb = x + (wrow + lrow) * 256 + g * 8;

#define XLD(i)  do { const float* p_ = xb + ((i) >> 3) * (16 * 256) + ((i) & 7) * 32; \
                     lo[i] = *reinterpret_cast<const floatx4*>(p_);                    \
                     hi[i] = *reinterpret_cast<const floatx4*>(p_ + 4); } while (0)
#define XCVT(i) do { half8 f_;                                                         \
                     f_[0] = (_Float16)lo[i][0]; f_[1] = (_Float16)lo[i][1];           \
                     f_[2] = (_Float16)lo[i][2]; f_[3] = (_Float16)lo[i][3];           \
                     f_[4] = (_Float16)hi[i][0]; f_[5] = (_Float16)hi[i][1];           \
                     f_[6] = (_Float16)hi[i][2]; f_[7] = (_Float16)hi[i][3];           \
                     a[(i) >> 3][(i) & 7] = f_; } while (0)
#define SB()    __builtin_amdgcn_sched_barrier(0)

    XLD(0); XLD(1); XLD(2); XLD(3); SB();
    XLD(4);  XCVT(0);  SB();
    XLD(5);  XCVT(1);  SB();
    XLD(6);  XCVT(2);  SB();
    XLD(7);  XCVT(3);  SB();
    XLD(8);  XCVT(4);  SB();
    XLD(9);  XCVT(5);  SB();
    XLD(10); XCVT(6);  SB();
    XLD(11); XCVT(7);  SB();
    XLD(12); XCVT(8);  SB();
    XLD(13); XCVT(9);  SB();
    XLD(14); XCVT(10); SB();
    XLD(15); XCVT(11); SB();
    XCVT(12); XCVT(13); XCVT(14); XCVT(15); SB();

    float rp[2][4] = {{0, 0, 0, 0}, {0, 0, 0, 0}};
    const half8* Wv = reinterpret_cast<const half8*>(Wf);

#pragma unroll
    for (int n = 0; n < 16; ++n) {
        floatx4 c0 = {0, 0, 0, 0}, c1 = {0, 0, 0, 0};
#pragma unroll
        for (int kk = 0; kk < 8; ++kk) {
            half8 b = Wv[(n * 8 + kk) * 64 + lane];
            c0 = __builtin_amdgcn_mfma_f32_16x16x32_f16(a[0][kk], b, c0, 0, 0, 0);
            c1 = __builtin_amdgcn_mfma_f32_16x16x32_f16(a[1][kk], b, c1, 0, 0, 0);
        }
        const float kv = kreg[n];
#pragma unroll
        for (int r = 0; r < 4; ++r) {
            rp[0][r] += c0[r] * c0[r] * kv;
            rp[1][r] += c1[r] * c1[r] * kv;
        }
    }

    // Reduce over the 16 cols (lanes sharing g): shfl over lrow bits
#pragma unroll
    for (int s = 0; s < 2; ++s)
#pragma unroll
        for (int r = 0; r < 4; ++r) {
            float v = rp[s][r];
            v += __shfl_xor(v, 1);
            v += __shfl_xor(v, 2);
            v += __shfl_xor(v, 4);
            v += __shfl_xor(v, 8);
            rp[s][r] = v;
        }
    if (lrow == 0) {
#pragma unroll
        for (int s = 0; s < 2; ++s) {
            floatx4 o;
#pragma unroll
            for (int r = 0; r < 4; ++r) o[r] = rp[s][r] * WSCALE_INV + bs;
            *reinterpret_cast<floatx4*>(out + wrow + s * 16 + g * 4) = o;
        }
    }
}

extern "C" void kernel_launch(void* const* d_in, const int* in_sizes, int n_in,
                              void* d_out, int out_size, void* d_ws, size_t ws_size,
                              hipStream_t stream) {
    const float* x    = (const float*)d_in[0];
    const float* w    = (const float*)d_in[1];
    const float* dk   = (const float*)d_in[2];
    const float* bias = (const float*)d_in[3];
    float* out = (float*)d_out;
    float* ws  = (float*)d_ws;

    _Float16* Wf16 = (_Float16*)(ws + WF16_OFF);

    // W contraction (tiny)
    mpo_pairs<<<(8704 + 255) / 256, 256, 0, stream>>>(w, ws);
    mpo_step<<<(4096 + 255) / 256, 256, 0, stream>>>(ws + S0_OFF, ws + S1_OFF, ws + T1_OFF, 16, 4);
    mpo_step<<<(65536 + 255) / 256, 256, 0, stream>>>(ws + T1_OFF, ws + S2_OFF, ws + T2_OFF, 16, 16);
    mpo_step_final<<<(65536 + 255) / 256, 256, 0, stream>>>(ws + T2_OFF, ws + S3_OFF, Wf16);

    // Main fused GEMM + square + dot: 262144 rows / 32 per wave / 4 waves per block
    const int n_rows = in_sizes[0] / 256;          // 262144
    const int grid   = n_rows / (32 * 4);          // 2048
    mpo_main<<<grid, 256, 0, stream>>>(x, Wf16, dk, bias, out);
}

// Round 4
// 90.483 us; speedup vs baseline: 2.2048x; 1.8796x over previous
//
#include <hip/hip_runtime.h>
#include <hip/hip_bf16.h>

typedef _Float16 half8 __attribute__((ext_vector_type(8)));
typedef float    floatx4 __attribute__((ext_vector_type(4)));

#define WSCALE      4096.0f
#define WSCALE_INV  (1.0f/(4096.0f*4096.0f))

// ws layout (float offsets)
#define S0_OFF   0      // 256 floats  (1,16,4,4)
#define S1_OFF   256    // 4096        (16,16,4,4)
#define S2_OFF   4352   // 4096
#define S3_OFF   8448   // 256         (16,1,4,4)
#define T1_OFF   8704   // 4096        (16,16,16)
#define T2_OFF   12800  // 65536       (16,64,64)
#define WF16_OFF 78336  // 65536 _Float16, fragment-major; 16B-aligned

// ---- Pair-contract adjacent MPO cores into 4 supercores (l,r,4,4) ----
__global__ void mpo_pairs(const float* __restrict__ w, float* __restrict__ ws) {
    int idx = blockIdx.x * blockDim.x + threadIdx.x;
    int p, base, r, outoff;
    if      (idx < 256)  { p = 0; base = 0;    r = 16; outoff = S0_OFF; }
    else if (idx < 4352) { p = 1; base = 256;  r = 16; outoff = S1_OFF; }
    else if (idx < 8448) { p = 2; base = 4352; r = 16; outoff = S2_OFF; }
    else if (idx < 8704) { p = 3; base = 8448; r = 1;  outoff = S3_OFF; }
    else return;
    int li = idx - base;
    int mm = li & 3, kk = (li >> 2) & 3, ac = li >> 4;
    int c = ac % r, a = ac / r;
    int k1 = kk >> 1, k2 = kk & 1, m1 = mm >> 1, m2 = mm & 1;
    const int coreoff[8] = {0, 64, 1088, 2112, 3136, 4160, 5184, 6208};
    const float* A = w + coreoff[2 * p];       // (l,16,2,2)
    const float* B = w + coreoff[2 * p + 1];   // (16,r,2,2)
    float s = 0.f;
    for (int b = 0; b < 16; ++b)
        s += A[((a * 16 + b) * 2 + k1) * 2 + m1] * B[((b * r + c) * 2 + k2) * 2 + m2];
    ws[outoff + li] = s;   // S[a][c][k1*2+k2][m1*2+m2]
}

// ---- Generic TT step: T(16,dim,dim) x S(16,r,4,4) -> out(r,4dim,4dim) ----
__global__ void mpo_step(const float* __restrict__ T, const float* __restrict__ S,
                         float* __restrict__ out, int r, int dim) {
    int idx = blockIdx.x * blockDim.x + threadIdx.x;
    int D4 = dim * 4;
    int total = r * D4 * D4;
    if (idx >= total) return;
    int J4 = idx % D4; int t = idx / D4; int I4 = t % D4; int b = t / D4;
    int I = I4 >> 2, k = I4 & 3, J = J4 >> 2, m = J4 & 3;
    float s = 0.f;
    for (int a = 0; a < 16; ++a)
        s += T[(a * dim + I) * dim + J] * S[((a * r + b) * 4 + k) * 4 + m];
    out[idx] = s;
}

// ---- Final step fused with scale + fp16 + FRAGMENT-MAJOR layout ----
// W[k=I4][col=J4]; fragment index: strip n=col>>4, lrow=col&15,
// kk=k>>5, g=(k>>3)&3, j=k&7.  Lane (g*16+lrow) of read (n,kk) gets 8
// contiguous halves -> wave read is lane-linear 1024B.
__global__ void mpo_step_final(const float* __restrict__ T, const float* __restrict__ S,
                               _Float16* __restrict__ Wf) {
    int idx = blockIdx.x * blockDim.x + threadIdx.x;  // 65536
    int J4 = idx & 255; int I4 = idx >> 8;            // col, k
    int I = I4 >> 2, k = I4 & 3, J = J4 >> 2, m = J4 & 3;
    float s = 0.f;
    for (int a = 0; a < 16; ++a)
        s += T[(a * 64 + I) * 64 + J] * S[(a * 4 + k) * 4 + m];
    int n = J4 >> 4, lr = J4 & 15, kk = I4 >> 5, gg = (I4 >> 3) & 3, j = I4 & 7;
    Wf[(((n * 8 + kk) * 64) + gg * 16 + lr) * 8 + j] = (_Float16)(s * WSCALE);
}

// ---- Main fused kernel: no LDS, no barriers. Each wave owns 32 rows. ----
// Register-pressure discipline:
//   * x load+cvt: depth-4 ring of floatx4 temps (32 VGPR), sched_barrier-pinned
//   * n-loop NOT unrolled (#pragma unroll 1): <=8 B-load temps in flight
//   * dk loaded per-iteration from L1 (no kreg[16])
//   * __launch_bounds__(256,2): RA cap 256 so a[2][8] stays resident
__global__ __launch_bounds__(256, 2)
void mpo_main(const float* __restrict__ x, const _Float16* __restrict__ Wf,
              const float* __restrict__ dk, const float* __restrict__ bias,
              float* __restrict__ out) {
    const int tid  = threadIdx.x;
    const int lane = tid & 63;
    const int wave = tid >> 6;
    const int lrow = lane & 15;   // A row / B,C col within tile
    const int g    = lane >> 4;   // k-group

    const long gw   = (long)blockIdx.x * 4 + wave;
    const long wrow = gw * 32;

    const float bs = bias[0];

    // ---- Pipelined load+convert of 32 rows x 256 K of x ----
    // fragment i: s=i>>3, kk=i&7; addr = (wrow + s*16 + lrow)*256 + g*8 + kk*32
    half8 a[2][8];
    floatx4 lo[4], hi[4];
    const float* xb = x + (wrow + lrow) * 256 + g * 8;

#define XLD(i)  do { const float* p_ = xb + ((i) >> 3) * (16 * 256) + ((i) & 7) * 32; \
                     lo[(i) & 3] = *reinterpret_cast<const floatx4*>(p_);              \
                     hi[(i) & 3] = *reinterpret_cast<const floatx4*>(p_ + 4); } while (0)
#define XCVT(i) do { half8 f_;                                                         \
                     f_[0] = (_Float16)lo[(i) & 3][0]; f_[1] = (_Float16)lo[(i) & 3][1]; \
                     f_[2] = (_Float16)lo[(i) & 3][2]; f_[3] = (_Float16)lo[(i) & 3][3]; \
                     f_[4] = (_Float16)hi[(i) & 3][0]; f_[5] = (_Float16)hi[(i) & 3][1]; \
                     f_[6] = (_Float16)hi[(i) & 3][2]; f_[7] = (_Float16)hi[(i) & 3][3]; \
                     a[(i) >> 3][(i) & 7] = f_; } while (0)
#define SB()    __builtin_amdgcn_sched_barrier(0)

    XLD(0); XLD(1); XLD(2); XLD(3); SB();
    XCVT(0);  XLD(4);  SB();
    XCVT(1);  XLD(5);  SB();
    XCVT(2);  XLD(6);  SB();
    XCVT(3);  XLD(7);  SB();
    XCVT(4);  XLD(8);  SB();
    XCVT(5);  XLD(9);  SB();
    XCVT(6);  XLD(10); SB();
    XCVT(7);  XLD(11); SB();
    XCVT(8);  XLD(12); SB();
    XCVT(9);  XLD(13); SB();
    XCVT(10); XLD(14); SB();
    XCVT(11); XLD(15); SB();
    XCVT(12); XCVT(13); XCVT(14); XCVT(15); SB();

    float rp[2][4] = {{0, 0, 0, 0}, {0, 0, 0, 0}};
    const half8* Wv = reinterpret_cast<const half8*>(Wf);
    const float* dkl = dk + lrow;

#pragma unroll 1
    for (int n = 0; n < 16; ++n) {
        const float kv = dkl[n * 16];
        const half8* Wn = Wv + n * 512 + lane;
        floatx4 c0 = {0, 0, 0, 0}, c1 = {0, 0, 0, 0};
#pragma unroll
        for (int kk = 0; kk < 8; ++kk) {
            half8 b = Wn[kk * 64];
            c0 = __builtin_amdgcn_mfma_f32_16x16x32_f16(a[0][kk], b, c0, 0, 0, 0);
            c1 = __builtin_amdgcn_mfma_f32_16x16x32_f16(a[1][kk], b, c1, 0, 0, 0);
        }
#pragma unroll
        for (int r = 0; r < 4; ++r) {
            rp[0][r] += c0[r] * c0[r] * kv;
            rp[1][r] += c1[r] * c1[r] * kv;
        }
    }

    // Reduce over the 16 cols (lanes sharing g): shfl over lrow bits
#pragma unroll
    for (int s = 0; s < 2; ++s)
#pragma unroll
        for (int r = 0; r < 4; ++r) {
            float v = rp[s][r];
            v += __shfl_xor(v, 1);
            v += __shfl_xor(v, 2);
            v += __shfl_xor(v, 4);
            v += __shfl_xor(v, 8);
            rp[s][r] = v;
        }
    if (lrow == 0) {
#pragma unroll
        for (int s = 0; s < 2; ++s) {
            floatx4 o;
#pragma unroll
            for (int r = 0; r < 4; ++r) o[r] = rp[s][r] * WSCALE_INV + bs;
            *reinterpret_cast<floatx4*>(out + wrow + s * 16 + g * 4) = o;
        }
    }
}

extern "C" void kernel_launch(void* const* d_in, const int* in_sizes, int n_in,
                              void* d_out, int out_size, void* d_ws, size_t ws_size,
                              hipStream_t stream) {
    const float* x    = (const float*)d_in[0];
    const float* w    = (const float*)d_in[1];
    const float* dk   = (const float*)d_in[2];
    const float* bias = (const float*)d_in[3];
    float* out = (float*)d_out;
    float* ws  = (float*)d_ws;

    _Float16* Wf16 = (_Float16*)(ws + WF16_OFF);

    // W contraction (tiny)
    mpo_pairs<<<(8704 + 255) / 256, 256, 0, stream>>>(w, ws);
    mpo_step<<<(4096 + 255) / 256, 256, 0, stream>>>(ws + S0_OFF, ws + S1_OFF, ws + T1_OFF, 16, 4);
    mpo_step<<<(65536 + 255) / 256, 256, 0, stream>>>(ws + T1_OFF, ws + S2_OFF, ws + T2_OFF, 16, 16);
    mpo_step_final<<<(65536 + 255) / 256, 256, 0, stream>>>(ws + T2_OFF, ws + S3_OFF, Wf16);

    // Main fused GEMM + square + dot: 262144 rows / 32 per wave / 4 waves per block
    const int n_rows = in_sizes[0] / 256;          // 262144
    const int grid   = n_rows / (32 * 4);          // 2048
    mpo_main<<<grid, 256, 0, stream>>>(x, Wf16, dk, bias, out);
}

// Round 5
// 71.849 us; speedup vs baseline: 2.7767x; 1.2593x over previous
//
#include <hip/hip_runtime.h>
#include <hip/hip_bf16.h>

typedef _Float16 half8 __attribute__((ext_vector_type(8)));
typedef float    floatx4 __attribute__((ext_vector_type(4)));

#define WSCALE      4096.0f
#define WSCALE_INV  (1.0f/(4096.0f*4096.0f))

// ws layout (float offsets)
#define S0_OFF   0      // 256 floats  (1,16,4,4)
#define S1_OFF   256    // 4096        (16,16,4,4)
#define S2_OFF   4352   // 4096
#define S3_OFF   8448   // 256         (16,1,4,4)
#define T1_OFF   8704   // 4096        (16,16,16)
#define T2_OFF   12800  // 65536       (16,64,64)
#define WF16_OFF 78336  // 65536 _Float16, fragment-major; 16B-aligned

// ---- Pair-contract adjacent MPO cores into 4 supercores (l,r,4,4) ----
__global__ void mpo_pairs(const float* __restrict__ w, float* __restrict__ ws) {
    int idx = blockIdx.x * blockDim.x + threadIdx.x;
    int p, base, r, outoff;
    if      (idx < 256)  { p = 0; base = 0;    r = 16; outoff = S0_OFF; }
    else if (idx < 4352) { p = 1; base = 256;  r = 16; outoff = S1_OFF; }
    else if (idx < 8448) { p = 2; base = 4352; r = 16; outoff = S2_OFF; }
    else if (idx < 8704) { p = 3; base = 8448; r = 1;  outoff = S3_OFF; }
    else return;
    int li = idx - base;
    int mm = li & 3, kk = (li >> 2) & 3, ac = li >> 4;
    int c = ac % r, a = ac / r;
    int k1 = kk >> 1, k2 = kk & 1, m1 = mm >> 1, m2 = mm & 1;
    const int coreoff[8] = {0, 64, 1088, 2112, 3136, 4160, 5184, 6208};
    const float* A = w + coreoff[2 * p];       // (l,16,2,2)
    const float* B = w + coreoff[2 * p + 1];   // (16,r,2,2)
    float s = 0.f;
    for (int b = 0; b < 16; ++b)
        s += A[((a * 16 + b) * 2 + k1) * 2 + m1] * B[((b * r + c) * 2 + k2) * 2 + m2];
    ws[outoff + li] = s;   // S[a][c][k1*2+k2][m1*2+m2]
}

// ---- Generic TT step: T(16,dim,dim) x S(16,r,4,4) -> out(r,4dim,4dim) ----
__global__ void mpo_step(const float* __restrict__ T, const float* __restrict__ S,
                         float* __restrict__ out, int r, int dim) {
    int idx = blockIdx.x * blockDim.x + threadIdx.x;
    int D4 = dim * 4;
    int total = r * D4 * D4;
    if (idx >= total) return;
    int J4 = idx % D4; int t = idx / D4; int I4 = t % D4; int b = t / D4;
    int I = I4 >> 2, k = I4 & 3, J = J4 >> 2, m = J4 & 3;
    float s = 0.f;
    for (int a = 0; a < 16; ++a)
        s += T[(a * dim + I) * dim + J] * S[((a * r + b) * 4 + k) * 4 + m];
    out[idx] = s;
}

// ---- Final step fused with scale + fp16 + FRAGMENT-MAJOR layout ----
// W[k=I4][col=J4]; fragment index: strip n=col>>4, lrow=col&15,
// kk=k>>5, g=(k>>3)&3, j=k&7.  Lane (g*16+lrow) of chunk (n,kk) gets 8
// contiguous halves -> wave read is lane-linear 1024B.
__global__ void mpo_step_final(const float* __restrict__ T, const float* __restrict__ S,
                               _Float16* __restrict__ Wf) {
    int idx = blockIdx.x * blockDim.x + threadIdx.x;  // 65536
    int J4 = idx & 255; int I4 = idx >> 8;            // col, k
    int I = I4 >> 2, k = I4 & 3, J = J4 >> 2, m = J4 & 3;
    float s = 0.f;
    for (int a = 0; a < 16; ++a)
        s += T[(a * 64 + I) * 64 + J] * S[(a * 4 + k) * 4 + m];
    int n = J4 >> 4, lr = J4 & 15, kk = I4 >> 5, gg = (I4 >> 3) & 3, j = I4 & 7;
    Wf[(((n * 8 + kk) * 64) + gg * 16 + lr) * 8 + j] = (_Float16)(s * WSCALE);
}

// ---- Main fused kernel ----
// 256 blocks x 1024 threads, ALL of W (128 KB fp16) staged in dynamic LDS
// once per block. One barrier total. VMEM pipe does nothing but stream x;
// B fragments come from LDS (canonical lane-linear ds_read_b128).
// 16 rows/wave x 4 passes; ~100 VGPR -> 4 waves/SIMD.
__global__ __launch_bounds__(1024, 4)
void mpo_main(const float* __restrict__ x, const _Float16* __restrict__ Wf,
              const float* __restrict__ dk, const float* __restrict__ bias,
              float* __restrict__ out) {
    extern __shared__ _Float16 Wl[];   // 65536 halves = 128 KB

    const int tid  = threadIdx.x;
    const int lane = tid & 63;
    const int wave = tid >> 6;        // 0..15
    const int lrow = lane & 15;       // A row / C col within tile
    const int g    = lane >> 4;       // k-group

    // ---- Stage all of W into LDS (8192 chunks of 16B, 1024 threads x 8) ----
    {
        const floatx4* src = reinterpret_cast<const floatx4*>(Wf);
        floatx4* dst = reinterpret_cast<floatx4*>(Wl);
#pragma unroll
        for (int i = 0; i < 8; ++i)
            dst[tid + i * 1024] = src[tid + i * 1024];
    }
    const float bs = bias[0];
    __syncthreads();   // the only barrier

    const long blockbase = (long)blockIdx.x * 1024;
    const half8* Wv = reinterpret_cast<const half8*>(Wl);
    const float* dkl = dk + lrow;

#define SB()    __builtin_amdgcn_sched_barrier(0)

#pragma unroll 1
    for (int pass = 0; pass < 4; ++pass) {
        const long wrow = blockbase + pass * 256 + wave * 16;

        // ---- Pipelined load+convert of 16 rows x 256 K of x ----
        // fragment i (=kk): addr = (wrow + lrow)*256 + g*8 + i*32
        half8 a[8];
        floatx4 lo[4], hi[4];
        const float* xb = x + (wrow + lrow) * 256 + g * 8;

#define XLD(i)  do { const float* p_ = xb + (i) * 32;                                    \
                     lo[(i) & 3] = *reinterpret_cast<const floatx4*>(p_);                \
                     hi[(i) & 3] = *reinterpret_cast<const floatx4*>(p_ + 4); } while (0)
#define XCVT(i) do { half8 f_;                                                           \
                     f_[0] = (_Float16)lo[(i) & 3][0]; f_[1] = (_Float16)lo[(i) & 3][1]; \
                     f_[2] = (_Float16)lo[(i) & 3][2]; f_[3] = (_Float16)lo[(i) & 3][3]; \
                     f_[4] = (_Float16)hi[(i) & 3][0]; f_[5] = (_Float16)hi[(i) & 3][1]; \
                     f_[6] = (_Float16)hi[(i) & 3][2]; f_[7] = (_Float16)hi[(i) & 3][3]; \
                     a[(i)] = f_; } while (0)

        XLD(0); XLD(1); XLD(2); XLD(3); SB();
        XCVT(0); XLD(4); SB();
        XCVT(1); XLD(5); SB();
        XCVT(2); XLD(6); SB();
        XCVT(3); XLD(7); SB();
        XCVT(4); XCVT(5); XCVT(6); XCVT(7); SB();

        float rp[4] = {0, 0, 0, 0};

#pragma unroll 1
        for (int n = 0; n < 16; ++n) {
            const float kv = dkl[n * 16];
            const half8* Wn = Wv + n * 512 + lane;
            floatx4 c0 = {0, 0, 0, 0}, c1 = {0, 0, 0, 0};
#pragma unroll
            for (int kk = 0; kk < 8; kk += 2) {
                half8 b0 = Wn[kk * 64];
                half8 b1 = Wn[kk * 64 + 64];
                c0 = __builtin_amdgcn_mfma_f32_16x16x32_f16(a[kk],     b0, c0, 0, 0, 0);
                c1 = __builtin_amdgcn_mfma_f32_16x16x32_f16(a[kk + 1], b1, c1, 0, 0, 0);
            }
            // c0+c1 is the full k-sum (linear), square after summing
#pragma unroll
            for (int r = 0; r < 4; ++r) {
                float y = c0[r] + c1[r];
                rp[r] += y * y * kv;
            }
        }

        // Reduce over the 16 cols (lanes sharing g): shfl over lrow bits
#pragma unroll
        for (int r = 0; r < 4; ++r) {
            float v = rp[r];
            v += __shfl_xor(v, 1);
            v += __shfl_xor(v, 2);
            v += __shfl_xor(v, 4);
            v += __shfl_xor(v, 8);
            rp[r] = v;
        }
        if (lrow == 0) {
            floatx4 o;
#pragma unroll
            for (int r = 0; r < 4; ++r) o[r] = rp[r] * WSCALE_INV + bs;
            *reinterpret_cast<floatx4*>(out + wrow + g * 4) = o;
        }
    }
}

extern "C" void kernel_launch(void* const* d_in, const int* in_sizes, int n_in,
                              void* d_out, int out_size, void* d_ws, size_t ws_size,
                              hipStream_t stream) {
    const float* x    = (const float*)d_in[0];
    const float* w    = (const float*)d_in[1];
    const float* dk   = (const float*)d_in[2];
    const float* bias = (const float*)d_in[3];
    float* out = (float*)d_out;
    float* ws  = (float*)d_ws;

    _Float16* Wf16 = (_Float16*)(ws + WF16_OFF);

    // Allow 128 KB dynamic LDS (host-side attribute, not a stream op; safe
    // under graph capture). Idempotent.
    static bool attr_set = false;
    if (!attr_set) {
        hipFuncSetAttribute((const void*)mpo_main,
                            hipFuncAttributeMaxDynamicSharedMemorySize, 131072);
        attr_set = true;
    }

    // W contraction (tiny)
    mpo_pairs<<<(8704 + 255) / 256, 256, 0, stream>>>(w, ws);
    mpo_step<<<(4096 + 255) / 256, 256, 0, stream>>>(ws + S0_OFF, ws + S1_OFF, ws + T1_OFF, 16, 4);
    mpo_step<<<(65536 + 255) / 256, 256, 0, stream>>>(ws + T1_OFF, ws + S2_OFF, ws + T2_OFF, 16, 16);
    mpo_step_final<<<(65536 + 255) / 256, 256, 0, stream>>>(ws + T2_OFF, ws + S3_OFF, Wf16);

    // Main fused GEMM + square + dot: 256 blocks x 1024 threads, 128 KB LDS
    mpo_main<<<256, 1024, 131072, stream>>>(x, Wf16, dk, bias, out);
}